// Round 5
// baseline (62.200 us; speedup 1.0000x reference)
//
#include <hip/hip_runtime.h>
#include <cstdint>
#include <cstddef>

// Problem constants (from reference setup_inputs):
//   x:      (B=16, TB=64, H=128, W=128) float32, values in {0.0, 1.0} exactly
//   rp_map: (C=64, NB=4) int32 indices into TB
//   out:    (B, C=64, H, W) float32, out[b,c,h,w] = sum_nb x[b, rp[c][nb], h, w] * 2^nb
constexpr int Bn = 16;
constexpr int TBn = 64;
constexpr int Hn = 128;
constexpr int Wn = 128;
constexpr int Cn = 64;
constexpr int HW = Hn * Wn;                   // 16384 pixels per (b, plane)
constexpr int TOTAL_PIX = Bn * HW;            // 262144
constexpr int GROUPS = TOTAL_PIX / 4;         // 65536 float4 pixel-groups
constexpr int GROUPS_PER_BLOCK = 256;
constexpr int PBLKS = GROUPS / GROUPS_PER_BLOCK; // 256 pixel-blocks
constexpr int CH_SPLIT = 4;                   // channel quarters
constexpr int CH_PER = Cn / CH_SPLIT;         // 16 channels per thread

__global__ __launch_bounds__(256) void rp_pack_f4(
    const float* __restrict__ x,
    const int* __restrict__ rp,
    float* __restrict__ out)
{
    // Stage rp_map (64 channels x int4) into LDS once per block.
    __shared__ int4 s_rp[Cn];
    if (threadIdx.x < Cn) {
        s_rp[threadIdx.x] = reinterpret_cast<const int4*>(rp)[threadIdx.x];
    }
    __syncthreads();

    // Adjacent groups of 4 blocks share the same pixel range (the redundant
    // x reads become L2-temporal hits); q picks the 16-channel quarter.
    const int bid = blockIdx.x;
    const int q = bid & 3;
    const int pblk = bid >> 2;

    const int g = pblk * GROUPS_PER_BLOCK + threadIdx.x; // 0..GROUPS-1
    const int b = g >> 12;               // 4096 groups per image
    const int pix = (g & 4095) << 2;     // pixel offset within the image

    const float* xb = x + (size_t)b * TBn * HW + pix;
    float* ob = out + (size_t)b * Cn * HW + (size_t)(q * CH_PER) * HW + pix;

    // Build per-pixel 64-bit masks from 64 coalesced float4 loads
    // (16 B/lane = 1 KiB per wave per instruction). x is exactly 0.0/1.0,
    // so bit 23 of the float encoding == (v == 1.0f).
    uint64_t m0 = 0, m1 = 0, m2 = 0, m3 = 0;
    #pragma unroll
    for (int t = 0; t < TBn; ++t) {
        const float4 v = *reinterpret_cast<const float4*>(xb + (size_t)t * HW);
        m0 |= (uint64_t)((__float_as_uint(v.x) >> 23) & 1u) << t;
        m1 |= (uint64_t)((__float_as_uint(v.y) >> 23) & 1u) << t;
        m2 |= (uint64_t)((__float_as_uint(v.z) >> 23) & 1u) << t;
        m3 |= (uint64_t)((__float_as_uint(v.w) >> 23) & 1u) << t;
    }

    // This thread's 16 channels: extract 4 bits per pixel, pack, store float4.
    const int c0 = q * CH_PER;
    #pragma unroll
    for (int ci = 0; ci < CH_PER; ++ci) {
        const int4 r = s_rp[c0 + ci];
        const unsigned i0 = (unsigned)r.x;
        const unsigned i1 = (unsigned)r.y;
        const unsigned i2 = (unsigned)r.z;
        const unsigned i3 = (unsigned)r.w;

        float4 o;
        o.x = (float)((unsigned)((m0 >> i0) & 1ull)
                    | ((unsigned)((m0 >> i1) & 1ull) << 1)
                    | ((unsigned)((m0 >> i2) & 1ull) << 2)
                    | ((unsigned)((m0 >> i3) & 1ull) << 3));
        o.y = (float)((unsigned)((m1 >> i0) & 1ull)
                    | ((unsigned)((m1 >> i1) & 1ull) << 1)
                    | ((unsigned)((m1 >> i2) & 1ull) << 2)
                    | ((unsigned)((m1 >> i3) & 1ull) << 3));
        o.z = (float)((unsigned)((m2 >> i0) & 1ull)
                    | ((unsigned)((m2 >> i1) & 1ull) << 1)
                    | ((unsigned)((m2 >> i2) & 1ull) << 2)
                    | ((unsigned)((m2 >> i3) & 1ull) << 3));
        o.w = (float)((unsigned)((m3 >> i0) & 1ull)
                    | ((unsigned)((m3 >> i1) & 1ull) << 1)
                    | ((unsigned)((m3 >> i2) & 1ull) << 2)
                    | ((unsigned)((m3 >> i3) & 1ull) << 3));

        *reinterpret_cast<float4*>(ob + (size_t)ci * HW) = o;
    }
}

extern "C" void kernel_launch(void* const* d_in, const int* in_sizes, int n_in,
                              void* d_out, int out_size, void* d_ws, size_t ws_size,
                              hipStream_t stream) {
    const float* x = (const float*)d_in[0];
    const int* rp = (const int*)d_in[1];
    float* out = (float*)d_out;

    constexpr int BLOCK = 256;
    constexpr int GRID = PBLKS * CH_SPLIT; // 1024 blocks = 4096 waves
    rp_pack_f4<<<GRID, BLOCK, 0, stream>>>(x, rp, out);
}

// Round 6
// 26.461 us; speedup vs baseline: 2.3506x; 2.3506x over previous
//
#include <hip/hip_runtime.h>
#include <cstdint>
#include <cstddef>

// Problem constants (from reference setup_inputs):
//   x:      (B=16, TB=64, H=128, W=128) float32, values in {0.0, 1.0} exactly
//   rp_map: (C=64, NB=4) int32 indices into TB
//   out:    (B, C=64, H, W) float32, out[b,c,h,w] = sum_nb x[b, rp[c][nb], h, w] * 2^nb
constexpr int Bn = 16;
constexpr int TBn = 64;
constexpr int Hn = 128;
constexpr int Wn = 128;
constexpr int Cn = 64;
constexpr int HW = Hn * Wn;                 // 16384 pixels per (b, plane)
constexpr int TOTAL_PIX = Bn * HW;          // 262144
constexpr int PIX_PER_BLOCK = 256;          // 64 float4-groups per block
constexpr int BLOCKS = TOTAL_PIX / PIX_PER_BLOCK;   // 1024
constexpr int BLOCKS_PER_IMG = HW / PIX_PER_BLOCK;  // 64
// LDS mask row stride: 16 u16 payload + 4 pad (40 B rows de-phase banks)
constexpr int MROW = 20;

__global__ __launch_bounds__(256) void rp_pack_lds(
    const float* __restrict__ x,
    const int* __restrict__ rp,
    float* __restrict__ out)
{
    __shared__ int4 s_rp[Cn];
    __shared__ unsigned short m16[64 * MROW]; // [group g][pixel p*4 + quarter q]

    if (threadIdx.x < Cn) {
        s_rp[threadIdx.x] = reinterpret_cast<const int4*>(rp)[threadIdx.x];
    }

    const int b = blockIdx.x >> 6;             // 64 blocks per image
    const int pix0 = (blockIdx.x & 63) << 8;   // 256 pixels per block
    const int g = threadIdx.x & 63;            // float4 group within block
    const int q = threadIdx.x >> 6;            // wave index = plane/channel quarter

    // ---- Phase 1: wave q loads planes q*16..q*16+15 for all 64 groups. ----
    // Each float4 load instruction is 64 lanes x 16 B = 1 KiB contiguous.
    // x is exactly 0.0f/1.0f: bit 23 of the encoding == (v == 1.0f).
    const float* xb = x + (size_t)b * TBn * HW + (size_t)(q * 16) * HW + pix0 + g * 4;

    uint32_t p0 = 0, p1 = 0, p2 = 0, p3 = 0;
    #pragma unroll
    for (int i = 0; i < 16; ++i) {
        const float4 v = *reinterpret_cast<const float4*>(xb + (size_t)i * HW);
        p0 |= ((__float_as_uint(v.x) >> 23) & 1u) << i;
        p1 |= ((__float_as_uint(v.y) >> 23) & 1u) << i;
        p2 |= ((__float_as_uint(v.z) >> 23) & 1u) << i;
        p3 |= ((__float_as_uint(v.w) >> 23) & 1u) << i;
    }

    // Little-endian: quarter q lands at bits [q*16, q*16+16) of the u64 at
    // byte offset (g*MROW + p*4)*2 — so a plain u64 LDS read reassembles the
    // full 64-plane mask for pixel p of group g.
    unsigned short* row = &m16[g * MROW];
    row[0 * 4 + q] = (unsigned short)p0;
    row[1 * 4 + q] = (unsigned short)p1;
    row[2 * 4 + q] = (unsigned short)p2;
    row[3 * 4 + q] = (unsigned short)p3;

    __syncthreads();

    // ---- Phase 2: thread (g, cq) computes channels cq*16..cq*16+15 for its
    // 4 pixels and stores them as float4 (1 KiB per store instruction). ----
    const uint64_t m0 = *reinterpret_cast<const uint64_t*>(&row[0]);
    const uint64_t m1 = *reinterpret_cast<const uint64_t*>(&row[4]);
    const uint64_t m2 = *reinterpret_cast<const uint64_t*>(&row[8]);
    const uint64_t m3 = *reinterpret_cast<const uint64_t*>(&row[12]);

    const int c0 = q * 16;
    float* ob = out + (size_t)b * Cn * HW + (size_t)c0 * HW + pix0 + g * 4;

    #pragma unroll
    for (int ci = 0; ci < 16; ++ci) {
        const int4 r = s_rp[c0 + ci];
        const unsigned i0 = (unsigned)r.x;
        const unsigned i1 = (unsigned)r.y;
        const unsigned i2 = (unsigned)r.z;
        const unsigned i3 = (unsigned)r.w;

        float4 o;
        o.x = (float)((unsigned)((m0 >> i0) & 1ull)
                    | ((unsigned)((m0 >> i1) & 1ull) << 1)
                    | ((unsigned)((m0 >> i2) & 1ull) << 2)
                    | ((unsigned)((m0 >> i3) & 1ull) << 3));
        o.y = (float)((unsigned)((m1 >> i0) & 1ull)
                    | ((unsigned)((m1 >> i1) & 1ull) << 1)
                    | ((unsigned)((m1 >> i2) & 1ull) << 2)
                    | ((unsigned)((m1 >> i3) & 1ull) << 3));
        o.z = (float)((unsigned)((m2 >> i0) & 1ull)
                    | ((unsigned)((m2 >> i1) & 1ull) << 1)
                    | ((unsigned)((m2 >> i2) & 1ull) << 2)
                    | ((unsigned)((m2 >> i3) & 1ull) << 3));
        o.w = (float)((unsigned)((m3 >> i0) & 1ull)
                    | ((unsigned)((m3 >> i1) & 1ull) << 1)
                    | ((unsigned)((m3 >> i2) & 1ull) << 2)
                    | ((unsigned)((m3 >> i3) & 1ull) << 3));

        *reinterpret_cast<float4*>(ob + (size_t)ci * HW) = o;
    }
}

extern "C" void kernel_launch(void* const* d_in, const int* in_sizes, int n_in,
                              void* d_out, int out_size, void* d_ws, size_t ws_size,
                              hipStream_t stream) {
    const float* x = (const float*)d_in[0];
    const int* rp = (const int*)d_in[1];
    float* out = (float*)d_out;

    constexpr int BLOCK = 256;
    rp_pack_lds<<<BLOCKS, BLOCK, 0, stream>>>(x, rp, out);
}